// Round 1
// baseline (377.220 us; speedup 1.0000x reference)
//
#include <hip/hip_runtime.h>

#define LUT_D   33
#define LUT_D2  (33*33)       // 1089
#define LUT_D3  (33*33*33)    // 35937
#define IMG_H   2160
#define IMG_W   3840
#define HW      (IMG_H*IMG_W) // 8294400
#define NLUT    8

// ---------------------------------------------------------------------------
// Kernel A: softmax-combine the 8 LUT banks into channel-interleaved float4
// cells: clut[l][(b*33+g)*33+r] = (ch0, ch1, ch2, 0)
// lut layout: [2][8][3][33][33][33]
// ---------------------------------------------------------------------------
__global__ void __launch_bounds__(256)
combine_lut_kernel(const float* __restrict__ lut,
                   const float* __restrict__ lc0,
                   const float* __restrict__ lc1,
                   float4* __restrict__ clut)
{
    int cell = blockIdx.x * blockDim.x + threadIdx.x;
    int l = blockIdx.y;
    if (cell >= LUT_D3) return;

    const float* lc = (l == 0) ? lc0 : lc1;
    float w[NLUT];
    float m = lc[0];
#pragma unroll
    for (int n = 1; n < NLUT; ++n) m = fmaxf(m, lc[n]);
    float s = 0.f;
#pragma unroll
    for (int n = 0; n < NLUT; ++n) { w[n] = expf(lc[n] - m); s += w[n]; }
    float inv = 1.f / s;

    const float* base = lut + (size_t)l * NLUT * 3 * LUT_D3 + cell;
    float acc0 = 0.f, acc1 = 0.f, acc2 = 0.f;
#pragma unroll
    for (int n = 0; n < NLUT; ++n) {
        float wn = w[n] * inv;
        acc0 = fmaf(wn, base[(n * 3 + 0) * LUT_D3], acc0);
        acc1 = fmaf(wn, base[(n * 3 + 1) * LUT_D3], acc1);
        acc2 = fmaf(wn, base[(n * 3 + 2) * LUT_D3], acc2);
    }
    clut[(size_t)l * LUT_D3 + cell] = make_float4(acc0, acc1, acc2, 0.f);
}

// ---------------------------------------------------------------------------
// One trilinear apply from an interleaved float4 LUT.
// Reference: x = clip(v,0,1)*(D-1); i = clip(floor(x),0,D-2); f = x - i
// corner stride: b-> D2, g-> D, r-> 1
// ---------------------------------------------------------------------------
#define LERP4(a, b, t) make_float4(fmaf((t), (b).x - (a).x, (a).x), \
                                   fmaf((t), (b).y - (a).y, (a).y), \
                                   fmaf((t), (b).z - (a).z, (a).z), 0.f)

__device__ __forceinline__ void apply_one(const float4* __restrict__ lut,
                                          float r, float g, float b,
                                          float& outr, float& outg, float& outb)
{
    float xr = fminf(fmaxf(r, 0.f), 1.f) * (float)(LUT_D - 1);
    float xg = fminf(fmaxf(g, 0.f), 1.f) * (float)(LUT_D - 1);
    float xb = fminf(fmaxf(b, 0.f), 1.f) * (float)(LUT_D - 1);
    int ir = min((int)xr, LUT_D - 2);
    int ig = min((int)xg, LUT_D - 2);
    int ib = min((int)xb, LUT_D - 2);
    float fr = xr - (float)ir;
    float fg = xg - (float)ig;
    float fb = xb - (float)ib;

    int idx = (ib * LUT_D + ig) * LUT_D + ir;
    float4 c000 = lut[idx];
    float4 c001 = lut[idx + 1];
    float4 c010 = lut[idx + LUT_D];
    float4 c011 = lut[idx + LUT_D + 1];
    float4 c100 = lut[idx + LUT_D2];
    float4 c101 = lut[idx + LUT_D2 + 1];
    float4 c110 = lut[idx + LUT_D2 + LUT_D];
    float4 c111 = lut[idx + LUT_D2 + LUT_D + 1];

    float4 c00 = LERP4(c000, c001, fr);
    float4 c01 = LERP4(c010, c011, fr);
    float4 c10 = LERP4(c100, c101, fr);
    float4 c11 = LERP4(c110, c111, fr);
    float4 c0  = LERP4(c00, c01, fg);
    float4 c1  = LERP4(c10, c11, fg);
    float4 c   = LERP4(c0, c1, fb);
    outr = c.x; outg = c.y; outb = c.z;
}

// ---------------------------------------------------------------------------
// Kernel B: per-pixel double LUT apply, 4 pixels/thread, float4 I/O.
// ---------------------------------------------------------------------------
__global__ void __launch_bounds__(256)
lut_apply_kernel(const float* __restrict__ gt,
                 const float4* __restrict__ clut,
                 float* __restrict__ out)
{
    int t = blockIdx.x * blockDim.x + threadIdx.x;  // one float4 (4 pixels)
    const float4* Rp = (const float4*)(gt);
    const float4* Gp = (const float4*)(gt + HW);
    const float4* Bp = (const float4*)(gt + 2 * HW);

    float4 r4 = Rp[t];
    float4 g4 = Gp[t];
    float4 b4 = Bp[t];

    const float4* lut0 = clut;
    const float4* lut1 = clut + LUT_D3;

    float rin[4] = { r4.x, r4.y, r4.z, r4.w };
    float gin[4] = { g4.x, g4.y, g4.z, g4.w };
    float bin[4] = { b4.x, b4.y, b4.z, b4.w };
    float rout[4], gout[4], bout[4];

#pragma unroll
    for (int k = 0; k < 4; ++k) {
        float r1, g1, b1;
        apply_one(lut0, rin[k], gin[k], bin[k], r1, g1, b1);
        apply_one(lut1, r1, g1, b1, rout[k], gout[k], bout[k]);
    }

    float4* Ro = (float4*)(out);
    float4* Go = (float4*)(out + HW);
    float4* Bo = (float4*)(out + 2 * HW);
    Ro[t] = make_float4(rout[0], rout[1], rout[2], rout[3]);
    Go[t] = make_float4(gout[0], gout[1], gout[2], gout[3]);
    Bo[t] = make_float4(bout[0], bout[1], bout[2], bout[3]);
}

extern "C" void kernel_launch(void* const* d_in, const int* in_sizes, int n_in,
                              void* d_out, int out_size, void* d_ws, size_t ws_size,
                              hipStream_t stream)
{
    const float* gt  = (const float*)d_in[0];
    const float* lut = (const float*)d_in[1];
    const float* lc0 = (const float*)d_in[2];
    const float* lc1 = (const float*)d_in[3];
    float*       out = (float*)d_out;
    float4*      clut = (float4*)d_ws;   // 2 * 35937 float4 = ~1.15 MB

    // Kernel A: combine LUTs (grid.y = which LUT)
    dim3 gridA((LUT_D3 + 255) / 256, 2);
    combine_lut_kernel<<<gridA, 256, 0, stream>>>(lut, lc0, lc1, clut);

    // Kernel B: apply. HW/4 threads, 4 pixels each.
    int nthreads = HW / 4;               // 2,073,600
    int nblocks  = nthreads / 256;       // 8100 exactly
    lut_apply_kernel<<<nblocks, 256, 0, stream>>>(gt, clut, out);
}

// Round 2
// 355.655 us; speedup vs baseline: 1.0606x; 1.0606x over previous
//
#include <hip/hip_runtime.h>
#include <hip/hip_fp16.h>

#define LUT_D   33
#define LUT_D2  1089
#define LUT_D3  35937
#define HW      8294400
#define NLUT    8
#define NPAIRE  (LUT_D2*32)   // 34848 pair-packed entries for LUT1

__device__ __forceinline__ void softmax8(const float* __restrict__ lc, float* w)
{
    float m = lc[0];
#pragma unroll
    for (int n = 1; n < NLUT; ++n) m = fmaxf(m, lc[n]);
    float s = 0.f;
#pragma unroll
    for (int n = 0; n < NLUT; ++n) { w[n] = expf(lc[n] - m); s += w[n]; }
    float inv = 1.f / s;
#pragma unroll
    for (int n = 0; n < NLUT; ++n) w[n] *= inv;
}

// ---------------------------------------------------------------------------
// Combine kernel: one launch builds both tables.
//   clut0  : float4[35937]  (ch-interleaved f32 cells, LUT0)
//   clut1h : uint4[34848]   (fp16 pair-packed LUT1: {c0,c1,c2}@r0, @r0+1)
// lut layout: [2][8][3][33][33][33]
// ---------------------------------------------------------------------------
__global__ void __launch_bounds__(256)
combine_kernel(const float* __restrict__ lut,
               const float* __restrict__ lc0,
               const float* __restrict__ lc1,
               float4* __restrict__ clut0,
               uint4* __restrict__ clut1h)
{
    int id = blockIdx.x * blockDim.x + threadIdx.x;
    if (id < LUT_D3) {
        float w[NLUT]; softmax8(lc0, w);
        const float* base = lut + id;                       // l = 0
        float a0 = 0.f, a1 = 0.f, a2 = 0.f;
#pragma unroll
        for (int n = 0; n < NLUT; ++n) {
            a0 = fmaf(w[n], base[(n*3 + 0) * LUT_D3], a0);
            a1 = fmaf(w[n], base[(n*3 + 1) * LUT_D3], a1);
            a2 = fmaf(w[n], base[(n*3 + 2) * LUT_D3], a2);
        }
        clut0[id] = make_float4(a0, a1, a2, 0.f);
    } else if (id < LUT_D3 + NPAIRE) {
        int e  = id - LUT_D3;
        int r0 = e & 31;
        int bg = e >> 5;                                    // b*33+g, 0..1088
        float w[NLUT]; softmax8(lc1, w);
        const float* base = lut + (size_t)NLUT * 3 * LUT_D3 + bg * LUT_D + r0;  // l = 1
        float a0=0.f, a1=0.f, a2=0.f, b0=0.f, b1=0.f, b2=0.f;
#pragma unroll
        for (int n = 0; n < NLUT; ++n) {
            const float* p0 = base + (n*3 + 0) * LUT_D3;
            const float* p1 = base + (n*3 + 1) * LUT_D3;
            const float* p2 = base + (n*3 + 2) * LUT_D3;
            a0 = fmaf(w[n], p0[0], a0);  b0 = fmaf(w[n], p0[1], b0);
            a1 = fmaf(w[n], p1[0], a1);  b1 = fmaf(w[n], p1[1], b1);
            a2 = fmaf(w[n], p2[0], a2);  b2 = fmaf(w[n], p2[1], b2);
        }
        __half2 h01 = __float22half2_rn(make_float2(a0, a1)); // c0@r, c1@r
        __half2 h23 = __float22half2_rn(make_float2(a2, b0)); // c2@r, c0@r+1
        __half2 h45 = __float22half2_rn(make_float2(b1, b2)); // c1@r+1, c2@r+1
        uint4 q;
        q.x = *(const unsigned int*)&h01;
        q.y = *(const unsigned int*)&h23;
        q.z = *(const unsigned int*)&h45;
        q.w = 0u;
        clut1h[e] = q;
    }
}

// ---------------------------------------------------------------------------
// Apply kernel: 2 lanes per pixel (lane parity = r-corner for stage 1,
// b-corner for stage 2), 4 pixels per lane pair, float4 I/O.
// ---------------------------------------------------------------------------
__global__ void __launch_bounds__(256)
lut_apply_pair(const float* __restrict__ gt,
               const float4* __restrict__ clut0,
               const uint4* __restrict__ clut1h,
               float* __restrict__ out)
{
    int t    = blockIdx.x * blockDim.x + threadIdx.x;
    int pair = t >> 1;
    int dr   = t & 1;

    const float4* Rp = (const float4*)gt;
    const float4* Gp = (const float4*)(gt + HW);
    const float4* Bp = (const float4*)(gt + 2 * HW);
    float4 r4 = Rp[pair], g4 = Gp[pair], b4 = Bp[pair];

    float rin[4] = { r4.x, r4.y, r4.z, r4.w };
    float gin[4] = { g4.x, g4.y, g4.z, g4.w };
    float bin[4] = { b4.x, b4.y, b4.z, b4.w };
    float rout[4], gout[4], bout[4];

#pragma unroll
    for (int k = 0; k < 4; ++k) {
        // ---------- stage 1: f32 LUT, lane pair covers r / r+1 ----------
        float xr = fminf(fmaxf(rin[k], 0.f), 1.f) * 32.f;
        float xg = fminf(fmaxf(gin[k], 0.f), 1.f) * 32.f;
        float xb = fminf(fmaxf(bin[k], 0.f), 1.f) * 32.f;
        int ir = min((int)xr, 31), ig = min((int)xg, 31), ib = min((int)xb, 31);
        float fr = xr - (float)ir, fg = xg - (float)ig, fb = xb - (float)ib;

        int idx = (ib * LUT_D + ig) * LUT_D + ir + dr;
        float4 c00 = clut0[idx];
        float4 c01 = clut0[idx + LUT_D];
        float4 c10 = clut0[idx + LUT_D2];
        float4 c11 = clut0[idx + LUT_D2 + LUT_D];

        float g0x = fmaf(fg, c01.x - c00.x, c00.x);
        float g1x = fmaf(fg, c11.x - c10.x, c10.x);
        float vx  = fmaf(fb, g1x - g0x, g0x);
        float g0y = fmaf(fg, c01.y - c00.y, c00.y);
        float g1y = fmaf(fg, c11.y - c10.y, c10.y);
        float vy  = fmaf(fb, g1y - g0y, g0y);
        float g0z = fmaf(fg, c01.z - c00.z, c00.z);
        float g1z = fmaf(fg, c11.z - c10.z, c10.z);
        float vz  = fmaf(fb, g1z - g0z, g0z);

        float ox = __shfl_xor(vx, 1);
        float oy = __shfl_xor(vy, 1);
        float oz = __shfl_xor(vz, 1);
        // out = v0 + fr*(v1-v0); bit-identical in both lanes (same fmaf args)
        float r1 = dr ? fmaf(fr, vx - ox, ox) : fmaf(fr, ox - vx, vx);
        float g1 = dr ? fmaf(fr, vy - oy, oy) : fmaf(fr, oy - vy, vy);
        float b1 = dr ? fmaf(fr, vz - oz, oz) : fmaf(fr, oz - vz, vz);

        // ---------- stage 2: fp16 pair-packed LUT, lane pair covers b / b+1 ----
        float xr2 = fminf(fmaxf(r1, 0.f), 1.f) * 32.f;
        float xg2 = fminf(fmaxf(g1, 0.f), 1.f) * 32.f;
        float xb2 = fminf(fmaxf(b1, 0.f), 1.f) * 32.f;
        int ir2 = min((int)xr2, 31), ig2 = min((int)xg2, 31), ib2 = min((int)xb2, 31);
        float fr2 = xr2 - (float)ir2, fg2 = xg2 - (float)ig2, fb2 = xb2 - (float)ib2;

        int ebase = ((ib2 + dr) * LUT_D + ig2) * 32 + ir2;
        uint4 q0 = clut1h[ebase];        // dg = 0
        uint4 q1 = clut1h[ebase + 32];   // dg = 1 (same b, g+1)

        float2 q0a = __half22float2(*(const __half2*)&q0.x); // c0@r, c1@r
        float2 q0b = __half22float2(*(const __half2*)&q0.y); // c2@r, c0@r+1
        float2 q0c = __half22float2(*(const __half2*)&q0.z); // c1@r+1, c2@r+1
        float s0x = fmaf(fr2, q0b.y - q0a.x, q0a.x);
        float s0y = fmaf(fr2, q0c.x - q0a.y, q0a.y);
        float s0z = fmaf(fr2, q0c.y - q0b.x, q0b.x);

        float2 q1a = __half22float2(*(const __half2*)&q1.x);
        float2 q1b = __half22float2(*(const __half2*)&q1.y);
        float2 q1c = __half22float2(*(const __half2*)&q1.z);
        float s1x = fmaf(fr2, q1b.y - q1a.x, q1a.x);
        float s1y = fmaf(fr2, q1c.x - q1a.y, q1a.y);
        float s1z = fmaf(fr2, q1c.y - q1b.x, q1b.x);

        float ux = fmaf(fg2, s1x - s0x, s0x);
        float uy = fmaf(fg2, s1y - s0y, s0y);
        float uz = fmaf(fg2, s1z - s0z, s0z);

        float wx = __shfl_xor(ux, 1);
        float wy = __shfl_xor(uy, 1);
        float wz = __shfl_xor(uz, 1);
        rout[k] = dr ? fmaf(fb2, ux - wx, wx) : fmaf(fb2, wx - ux, ux);
        gout[k] = dr ? fmaf(fb2, uy - wy, wy) : fmaf(fb2, wy - uy, uy);
        bout[k] = dr ? fmaf(fb2, uz - wz, wz) : fmaf(fb2, wz - uz, uz);
    }

    if (dr == 0) {
        ((float4*)out)[pair]          = make_float4(rout[0], rout[1], rout[2], rout[3]);
        ((float4*)(out + HW))[pair]   = make_float4(gout[0], gout[1], gout[2], gout[3]);
        ((float4*)(out + 2*HW))[pair] = make_float4(bout[0], bout[1], bout[2], bout[3]);
    }
}

extern "C" void kernel_launch(void* const* d_in, const int* in_sizes, int n_in,
                              void* d_out, int out_size, void* d_ws, size_t ws_size,
                              hipStream_t stream)
{
    const float* gt  = (const float*)d_in[0];
    const float* lut = (const float*)d_in[1];
    const float* lc0 = (const float*)d_in[2];
    const float* lc1 = (const float*)d_in[3];
    float*       out = (float*)d_out;

    float4* clut0  = (float4*)d_ws;                               // 575 KB
    uint4*  clut1h = (uint4*)((char*)d_ws + LUT_D3 * sizeof(float4)); // 557 KB

    int totalA = LUT_D3 + NPAIRE;   // 70785
    combine_kernel<<<(totalA + 255) / 256, 256, 0, stream>>>(lut, lc0, lc1, clut0, clut1h);

    int threadsB = HW / 2;          // 4,147,200 (2 lanes per pixel, 4 px per pair)
    lut_apply_pair<<<threadsB / 256, 256, 0, stream>>>(gt, clut0, clut1h, out);
}

// Round 3
// 276.071 us; speedup vs baseline: 1.3664x; 1.2883x over previous
//
#include <hip/hip_runtime.h>

#define LUT_D   33
#define LUT_D2  1089
#define LUT_D3  35937
#define HW      8294400
#define NLUT    8
#define NCELL   32768   // 32^3 cells per LUT

typedef float f4v __attribute__((ext_vector_type(4)));

__device__ __forceinline__ void softmax8(const float* __restrict__ lc, float* w)
{
    float m = lc[0];
#pragma unroll
    for (int n = 1; n < NLUT; ++n) m = fmaxf(m, lc[n]);
    float s = 0.f;
#pragma unroll
    for (int n = 0; n < NLUT; ++n) { w[n] = expf(lc[n] - m); s += w[n]; }
    float inv = 1.f / s;
#pragma unroll
    for (int n = 0; n < NLUT; ++n) w[n] *= inv;
}

// ---------------------------------------------------------------------------
// Combine kernel: build cell-granular u16 tables for both LUTs.
// Entry (per 32^3 cell): 8 corners x 3 channels as unorm16, 24 u16 = 48B
// packed tightly, stored in a 64B-aligned slot (last 16B unused).
// Value order: k = db*4 + dg*2 + dr, channels c0,c1,c2 -> vals[k*3+c].
// lut layout: [2][8][3][33][33][33]
// ---------------------------------------------------------------------------
__global__ void __launch_bounds__(256)
combine_cells(const float* __restrict__ lut,
              const float* __restrict__ lc0,
              const float* __restrict__ lc1,
              uint4* __restrict__ tab)
{
    int id = blockIdx.x * 256 + threadIdx.x;      // 0..65535 (both LUTs)
    int l    = id >> 15;
    int cell = id & (NCELL - 1);
    int ir = cell & 31, ig = (cell >> 5) & 31, ib = cell >> 10;

    float w[NLUT];
    softmax8(l ? lc1 : lc0, w);

    const float* base = lut + (size_t)l * NLUT * 3 * LUT_D3
                            + (ib * LUT_D + ig) * LUT_D + ir;
    float cv[24];
#pragma unroll
    for (int k = 0; k < 8; ++k) {
        int off = (k >> 2) * LUT_D2 + ((k >> 1) & 1) * LUT_D + (k & 1);
#pragma unroll
        for (int c = 0; c < 3; ++c) {
            float a = 0.f;
#pragma unroll
            for (int n = 0; n < NLUT; ++n)
                a = fmaf(w[n], base[(n * 3 + c) * LUT_D3 + off], a);
            cv[k * 3 + c] = a;       // in [0,1): convex comb of U[0,1)
        }
    }
    unsigned pk[12];
#pragma unroll
    for (int j = 0; j < 12; ++j) {
        unsigned lo = (unsigned)(fminf(cv[2*j],   1.f) * 65535.f + 0.5f);
        unsigned hi = (unsigned)(fminf(cv[2*j+1], 1.f) * 65535.f + 0.5f);
        pk[j] = lo | (hi << 16);
    }
    uint4* dst = tab + (size_t)id * 4;            // 64B slot per cell
    dst[0] = make_uint4(pk[0], pk[1], pk[2],  pk[3]);
    dst[1] = make_uint4(pk[4], pk[5], pk[6],  pk[7]);
    dst[2] = make_uint4(pk[8], pk[9], pk[10], pk[11]);
}

// ---------------------------------------------------------------------------
// One trilinear apply from a cell-granular u16 table.
// x* in [0,32]. Returns channel values scaled by 65535 (caller rescales).
// ---------------------------------------------------------------------------
__device__ __forceinline__ void stage(const uint4* __restrict__ tab,
                                      float xr, float xg, float xb,
                                      float& o0, float& o1, float& o2)
{
    int ir = min((int)xr, 31), ig = min((int)xg, 31), ib = min((int)xb, 31);
    float fr = xr - (float)ir, fg = xg - (float)ig, fb = xb - (float)ib;

    const uint4* p = tab + (size_t)((((ib << 5) | ig) << 5) | ir) * 4;
    uint4 q0 = p[0];
    uint4 q1 = p[1];
    uint4 q2 = p[2];

#define LOF(u) ((float)((u) & 0xffffu))
#define HIF(u) ((float)((u) >> 16))
    float k0c0=LOF(q0.x), k0c1=HIF(q0.x), k0c2=LOF(q0.y);
    float k1c0=HIF(q0.y), k1c1=LOF(q0.z), k1c2=HIF(q0.z);
    float k2c0=LOF(q0.w), k2c1=HIF(q0.w), k2c2=LOF(q1.x);
    float k3c0=HIF(q1.x), k3c1=LOF(q1.y), k3c2=HIF(q1.y);
    float k4c0=LOF(q1.z), k4c1=HIF(q1.z), k4c2=LOF(q1.w);
    float k5c0=HIF(q1.w), k5c1=LOF(q2.x), k5c2=HIF(q2.x);
    float k6c0=LOF(q2.y), k6c1=HIF(q2.y), k6c2=LOF(q2.z);
    float k7c0=HIF(q2.z), k7c1=LOF(q2.w), k7c2=HIF(q2.w);
#undef LOF
#undef HIF

    // r-lerp per (db,dg) group: pairs (k0,k1)=b0g0, (k2,k3)=b0g1, (k4,k5)=b1g0, (k6,k7)=b1g1
    float m0c0 = fmaf(fr, k1c0 - k0c0, k0c0);
    float m0c1 = fmaf(fr, k1c1 - k0c1, k0c1);
    float m0c2 = fmaf(fr, k1c2 - k0c2, k0c2);
    float m1c0 = fmaf(fr, k3c0 - k2c0, k2c0);
    float m1c1 = fmaf(fr, k3c1 - k2c1, k2c1);
    float m1c2 = fmaf(fr, k3c2 - k2c2, k2c2);
    float m2c0 = fmaf(fr, k5c0 - k4c0, k4c0);
    float m2c1 = fmaf(fr, k5c1 - k4c1, k4c1);
    float m2c2 = fmaf(fr, k5c2 - k4c2, k4c2);
    float m3c0 = fmaf(fr, k7c0 - k6c0, k6c0);
    float m3c1 = fmaf(fr, k7c1 - k6c1, k6c1);
    float m3c2 = fmaf(fr, k7c2 - k6c2, k6c2);

    float wg0 = 1.f - fg, wb0 = 1.f - fb;
    float w00 = wb0 * wg0, w01 = wb0 * fg, w10 = fb * wg0, w11 = fb * fg;

    o0 = fmaf(w00, m0c0, fmaf(w01, m1c0, fmaf(w10, m2c0, w11 * m3c0)));
    o1 = fmaf(w00, m0c1, fmaf(w01, m1c1, fmaf(w10, m2c1, w11 * m3c1)));
    o2 = fmaf(w00, m0c2, fmaf(w01, m1c2, fmaf(w10, m2c2, w11 * m3c2)));
}

// ---------------------------------------------------------------------------
// Apply kernel: 1 lane per pixel, 4 pixels/thread, float4 non-temporal I/O.
// ---------------------------------------------------------------------------
__global__ void __launch_bounds__(256)
lut_apply(const float* __restrict__ gt,
          const uint4* __restrict__ tab,
          float* __restrict__ out)
{
    int t = blockIdx.x * 256 + threadIdx.x;

    const f4v* Rp = (const f4v*)gt;
    const f4v* Gp = (const f4v*)(gt + HW);
    const f4v* Bp = (const f4v*)(gt + 2 * HW);
    f4v r4 = __builtin_nontemporal_load(Rp + t);
    f4v g4 = __builtin_nontemporal_load(Gp + t);
    f4v b4 = __builtin_nontemporal_load(Bp + t);

    const uint4* tab0 = tab;
    const uint4* tab1 = tab + (size_t)NCELL * 4;

    f4v ro, go, bo;
#pragma unroll
    for (int k = 0; k < 4; ++k) {
        float xr = fminf(fmaxf(r4[k], 0.f), 1.f) * 32.f;
        float xg = fminf(fmaxf(g4[k], 0.f), 1.f) * 32.f;
        float xb = fminf(fmaxf(b4[k], 0.f), 1.f) * 32.f;

        float a0, a1, a2;
        stage(tab0, xr, xg, xb, a0, a1, a2);

        // a* in [0, 65535]; rescale to coordinate domain [0,32] (a* >= 0 always)
        const float S = 32.f / 65535.f;
        float x2r = fminf(a0, 65535.f) * S;
        float x2g = fminf(a1, 65535.f) * S;
        float x2b = fminf(a2, 65535.f) * S;

        float b0, b1, b2;
        stage(tab1, x2r, x2g, x2b, b0, b1, b2);

        const float I = 1.f / 65535.f;
        ro[k] = b0 * I;
        go[k] = b1 * I;
        bo[k] = b2 * I;
    }

    __builtin_nontemporal_store(ro, (f4v*)out + t);
    __builtin_nontemporal_store(go, (f4v*)(out + HW) + t);
    __builtin_nontemporal_store(bo, (f4v*)(out + 2 * HW) + t);
}

extern "C" void kernel_launch(void* const* d_in, const int* in_sizes, int n_in,
                              void* d_out, int out_size, void* d_ws, size_t ws_size,
                              hipStream_t stream)
{
    const float* gt  = (const float*)d_in[0];
    const float* lut = (const float*)d_in[1];
    const float* lc0 = (const float*)d_in[2];
    const float* lc1 = (const float*)d_in[3];
    float*       out = (float*)d_out;
    uint4*       tab = (uint4*)d_ws;     // 2 * 32768 * 64B = 4 MiB

    combine_cells<<<65536 / 256, 256, 0, stream>>>(lut, lc0, lc1, tab);

    int nthreads = HW / 4;               // 2,073,600
    lut_apply<<<nthreads / 256, 256, 0, stream>>>(gt, tab, out);
}

// Round 4
// 270.425 us; speedup vs baseline: 1.3949x; 1.0209x over previous
//
#include <hip/hip_runtime.h>

#define LUT_D   33
#define LUT_D2  1089
#define LUT_D3  35937
#define HW      8294400
#define NLUT    8
#define NCELL   32768   // 32^3 cells per LUT

typedef float f4v __attribute__((ext_vector_type(4)));

__device__ __forceinline__ void softmax8(const float* __restrict__ lc, float* w)
{
    float m = lc[0];
#pragma unroll
    for (int n = 1; n < NLUT; ++n) m = fmaxf(m, lc[n]);
    float s = 0.f;
#pragma unroll
    for (int n = 0; n < NLUT; ++n) { w[n] = expf(lc[n] - m); s += w[n]; }
    float inv = 1.f / s;
#pragma unroll
    for (int n = 0; n < NLUT; ++n) w[n] *= inv;
}

// ---------------------------------------------------------------------------
// Pass 1: softmax-weighted combine, planar f32 output.
//   cg[l][c][idx] = sum_n w[l][n] * lut[l][n][c][idx]
// One thread per output element (2*3*35937 = 215,622). Coalesced loads:
// consecutive threads -> consecutive idx for fixed (l,c).
// lut layout: [2][8][3][33][33][33]
// ---------------------------------------------------------------------------
__global__ void __launch_bounds__(256)
combine_grid(const float* __restrict__ lut,
             const float* __restrict__ lc0,
             const float* __restrict__ lc1,
             float* __restrict__ cg)
{
    int t = blockIdx.x * 256 + threadIdx.x;
    if (t >= 2 * 3 * LUT_D3) return;
    int l   = t / (3 * LUT_D3);
    int rem = t - l * 3 * LUT_D3;          // c*LUT_D3 + idx

    float w[NLUT];
    softmax8(l ? lc1 : lc0, w);

    const float* base = lut + (size_t)l * NLUT * 3 * LUT_D3 + rem;
    float a = 0.f;
#pragma unroll
    for (int n = 0; n < NLUT; ++n)
        a = fmaf(w[n], base[(size_t)n * 3 * LUT_D3], a);
    cg[t] = a;
}

// ---------------------------------------------------------------------------
// Pass 2: build cell-granular u16 tables from the planar combined grid.
// Entry (per 32^3 cell): 8 corners x 3 channels as unorm16, 24 u16 = 48B
// in a 64B-aligned slot. Value order: k = db*4+dg*2+dr, vals[k*3+c].
// Consecutive threads differ in ir -> consecutive addresses (L1-friendly).
// ---------------------------------------------------------------------------
__global__ void __launch_bounds__(256)
cellify(const float* __restrict__ cg, uint4* __restrict__ tab)
{
    int id = blockIdx.x * 256 + threadIdx.x;      // 0..65535
    int l    = id >> 15;
    int cell = id & (NCELL - 1);
    int ir = cell & 31, ig = (cell >> 5) & 31, ib = cell >> 10;

    const float* g0 = cg + (size_t)l * 3 * LUT_D3 + (ib * LUT_D + ig) * LUT_D + ir;

    float cv[24];
#pragma unroll
    for (int c = 0; c < 3; ++c) {
        const float* p = g0 + (size_t)c * LUT_D3;
#pragma unroll
        for (int k = 0; k < 8; ++k) {
            int off = (k >> 2) * LUT_D2 + ((k >> 1) & 1) * LUT_D + (k & 1);
            cv[k * 3 + c] = p[off];
        }
    }
    unsigned pk[12];
#pragma unroll
    for (int j = 0; j < 12; ++j) {
        unsigned lo = (unsigned)(fminf(cv[2*j],   1.f) * 65535.f + 0.5f);
        unsigned hi = (unsigned)(fminf(cv[2*j+1], 1.f) * 65535.f + 0.5f);
        pk[j] = lo | (hi << 16);
    }
    uint4* dst = tab + (size_t)id * 4;            // 64B slot per cell
    dst[0] = make_uint4(pk[0], pk[1], pk[2],  pk[3]);
    dst[1] = make_uint4(pk[4], pk[5], pk[6],  pk[7]);
    dst[2] = make_uint4(pk[8], pk[9], pk[10], pk[11]);
}

// ---------------------------------------------------------------------------
// One trilinear apply from a cell-granular u16 table.
// x* in [0,32]. Returns channel values scaled by 65535 (caller rescales).
// ---------------------------------------------------------------------------
__device__ __forceinline__ void stage(const uint4* __restrict__ tab,
                                      float xr, float xg, float xb,
                                      float& o0, float& o1, float& o2)
{
    int ir = min((int)xr, 31), ig = min((int)xg, 31), ib = min((int)xb, 31);
    float fr = xr - (float)ir, fg = xg - (float)ig, fb = xb - (float)ib;

    const uint4* p = tab + (size_t)((((ib << 5) | ig) << 5) | ir) * 4;
    uint4 q0 = p[0];
    uint4 q1 = p[1];
    uint4 q2 = p[2];

#define LOF(u) ((float)((u) & 0xffffu))
#define HIF(u) ((float)((u) >> 16))
    float k0c0=LOF(q0.x), k0c1=HIF(q0.x), k0c2=LOF(q0.y);
    float k1c0=HIF(q0.y), k1c1=LOF(q0.z), k1c2=HIF(q0.z);
    float k2c0=LOF(q0.w), k2c1=HIF(q0.w), k2c2=LOF(q1.x);
    float k3c0=HIF(q1.x), k3c1=LOF(q1.y), k3c2=HIF(q1.y);
    float k4c0=LOF(q1.z), k4c1=HIF(q1.z), k4c2=LOF(q1.w);
    float k5c0=HIF(q1.w), k5c1=LOF(q2.x), k5c2=HIF(q2.x);
    float k6c0=LOF(q2.y), k6c1=HIF(q2.y), k6c2=LOF(q2.z);
    float k7c0=HIF(q2.z), k7c1=LOF(q2.w), k7c2=HIF(q2.w);
#undef LOF
#undef HIF

    float m0c0 = fmaf(fr, k1c0 - k0c0, k0c0);
    float m0c1 = fmaf(fr, k1c1 - k0c1, k0c1);
    float m0c2 = fmaf(fr, k1c2 - k0c2, k0c2);
    float m1c0 = fmaf(fr, k3c0 - k2c0, k2c0);
    float m1c1 = fmaf(fr, k3c1 - k2c1, k2c1);
    float m1c2 = fmaf(fr, k3c2 - k2c2, k2c2);
    float m2c0 = fmaf(fr, k5c0 - k4c0, k4c0);
    float m2c1 = fmaf(fr, k5c1 - k4c1, k4c1);
    float m2c2 = fmaf(fr, k5c2 - k4c2, k4c2);
    float m3c0 = fmaf(fr, k7c0 - k6c0, k6c0);
    float m3c1 = fmaf(fr, k7c1 - k6c1, k6c1);
    float m3c2 = fmaf(fr, k7c2 - k6c2, k6c2);

    float wg0 = 1.f - fg, wb0 = 1.f - fb;
    float w00 = wb0 * wg0, w01 = wb0 * fg, w10 = fb * wg0, w11 = fb * fg;

    o0 = fmaf(w00, m0c0, fmaf(w01, m1c0, fmaf(w10, m2c0, w11 * m3c0)));
    o1 = fmaf(w00, m0c1, fmaf(w01, m1c1, fmaf(w10, m2c1, w11 * m3c1)));
    o2 = fmaf(w00, m0c2, fmaf(w01, m1c2, fmaf(w10, m2c2, w11 * m3c2)));
}

// ---------------------------------------------------------------------------
// Apply kernel: 1 lane per pixel, 4 pixels/thread, float4 non-temporal I/O.
// ---------------------------------------------------------------------------
__global__ void __launch_bounds__(256)
lut_apply(const float* __restrict__ gt,
          const uint4* __restrict__ tab,
          float* __restrict__ out)
{
    int t = blockIdx.x * 256 + threadIdx.x;

    const f4v* Rp = (const f4v*)gt;
    const f4v* Gp = (const f4v*)(gt + HW);
    const f4v* Bp = (const f4v*)(gt + 2 * HW);
    f4v r4 = __builtin_nontemporal_load(Rp + t);
    f4v g4 = __builtin_nontemporal_load(Gp + t);
    f4v b4 = __builtin_nontemporal_load(Bp + t);

    const uint4* tab0 = tab;
    const uint4* tab1 = tab + (size_t)NCELL * 4;

    f4v ro, go, bo;
#pragma unroll
    for (int k = 0; k < 4; ++k) {
        float xr = fminf(fmaxf(r4[k], 0.f), 1.f) * 32.f;
        float xg = fminf(fmaxf(g4[k], 0.f), 1.f) * 32.f;
        float xb = fminf(fmaxf(b4[k], 0.f), 1.f) * 32.f;

        float a0, a1, a2;
        stage(tab0, xr, xg, xb, a0, a1, a2);

        const float S = 32.f / 65535.f;
        float x2r = fminf(a0, 65535.f) * S;
        float x2g = fminf(a1, 65535.f) * S;
        float x2b = fminf(a2, 65535.f) * S;

        float b0, b1, b2;
        stage(tab1, x2r, x2g, x2b, b0, b1, b2);

        const float I = 1.f / 65535.f;
        ro[k] = b0 * I;
        go[k] = b1 * I;
        bo[k] = b2 * I;
    }

    __builtin_nontemporal_store(ro, (f4v*)out + t);
    __builtin_nontemporal_store(go, (f4v*)(out + HW) + t);
    __builtin_nontemporal_store(bo, (f4v*)(out + 2 * HW) + t);
}

extern "C" void kernel_launch(void* const* d_in, const int* in_sizes, int n_in,
                              void* d_out, int out_size, void* d_ws, size_t ws_size,
                              hipStream_t stream)
{
    const float* gt  = (const float*)d_in[0];
    const float* lut = (const float*)d_in[1];
    const float* lc0 = (const float*)d_in[2];
    const float* lc1 = (const float*)d_in[3];
    float*       out = (float*)d_out;

    uint4* tab = (uint4*)d_ws;                         // 2*32768*64B = 4 MiB
    float* cg  = (float*)((char*)d_ws + (size_t)2 * NCELL * 64); // 862,488 B

    int n1 = 2 * 3 * LUT_D3;                           // 215,622
    combine_grid<<<(n1 + 255) / 256, 256, 0, stream>>>(lut, lc0, lc1, cg);

    cellify<<<(2 * NCELL) / 256, 256, 0, stream>>>(cg, tab);

    int nthreads = HW / 4;                             // 2,073,600
    lut_apply<<<nthreads / 256, 256, 0, stream>>>(gt, tab, out);
}